// Round 4
// baseline (384.632 us; speedup 1.0000x reference)
//
#include <hip/hip_runtime.h>
#include <hip/hip_bf16.h>

// Problem constants (from reference setup_inputs): B=8, N=2048, D=512
#define PB 8
#define PN 2048
#define PD 512
#define P_ASEM 0.6f

// Native clang vector type — required by __builtin_nontemporal_* (HIP's
// float4 is a class and is rejected).
typedef float v4f __attribute__((ext_vector_type(4)));

// ---------------------------------------------------------------------------
// Kernel 1: per-row dots. si[r] = x[r,:].Wi, sj[r] = x[r,:].Wj for r in [0,B*N)
// One wave per row; 2x v4f per lane; 64-lane butterfly reduction.
// ---------------------------------------------------------------------------
__global__ __launch_bounds__(256) void row_dots_kernel(
    const float* __restrict__ x,   // [B*N, D]
    const float* __restrict__ W,   // [2*D]
    float* __restrict__ si,        // [B*N]
    float* __restrict__ sj)        // [B*N]
{
    const int wave = threadIdx.x >> 6;            // 0..3
    const int lane = threadIdx.x & 63;
    const int row  = blockIdx.x * 4 + wave;       // grid = B*N/4

    const v4f* xr = (const v4f*)(x + (size_t)row * PD);
    const v4f* Wi = (const v4f*)(W);
    const v4f* Wj = (const v4f*)(W + PD);

    // D = 512 floats = 128 v4f; 64 lanes -> 2 v4f per lane
    v4f a0  = __builtin_nontemporal_load(xr + lane);
    v4f a1  = __builtin_nontemporal_load(xr + lane + 64);
    v4f wi0 = Wi[lane];
    v4f wi1 = Wi[lane + 64];
    v4f wj0 = Wj[lane];
    v4f wj1 = Wj[lane + 64];

    float acc_i = a0.x*wi0.x + a0.y*wi0.y + a0.z*wi0.z + a0.w*wi0.w
                + a1.x*wi1.x + a1.y*wi1.y + a1.z*wi1.z + a1.w*wi1.w;
    float acc_j = a0.x*wj0.x + a0.y*wj0.y + a0.z*wj0.z + a0.w*wj0.w
                + a1.x*wj1.x + a1.y*wj1.y + a1.z*wj1.z + a1.w*wj1.w;

    #pragma unroll
    for (int off = 32; off > 0; off >>= 1) {
        acc_i += __shfl_down(acc_i, off, 64);
        acc_j += __shfl_down(acc_j, off, 64);
    }
    if (lane == 0) {
        si[row] = acc_i;
        sj[row] = acc_j;
    }
}

// ---------------------------------------------------------------------------
// Kernel 2: out[b,i,j] = 0.6*sigmoid(si[b,i]+sj[b,j]+b0) + 0.4*adj[b,i,j]
// 4x v4f (16 floats, 64B) per thread: wave covers 4KB contiguous, 4
// outstanding 16B loads/thread for latency hiding. Nontemporal on the
// streaming adj/out (no reuse); sj stays cached (64KB/batch, L2-resident).
// ---------------------------------------------------------------------------
__device__ __forceinline__ float fsigmoid(float t) {
    return __frcp_rn(1.0f + __expf(-t));
}

__global__ __launch_bounds__(256) void blend_kernel(
    const float* __restrict__ adj,  // [B*N*N]
    const float* __restrict__ si,   // [B*N]
    const float* __restrict__ sj,   // [B*N]
    const float* __restrict__ bptr, // [1]
    float* __restrict__ out)        // [B*N*N]
{
    const size_t t  = (size_t)blockIdx.x * blockDim.x + threadIdx.x;
    const size_t o0 = t * 4;               // first v4f index (16 floats/thread)
    const int row   = (int)(o0 >> 9);      // / (N/4=512): combined b*N+i row
    const int jc    = (int)(o0 & 511);     // v4f column within row
    const int bidx  = row >> 11;           // / N -> batch

    const float s = si[row] + bptr[0];
    const v4f* sjr = (const v4f*)(sj + (size_t)bidx * PN);

    v4f av[4], sv[4];
    #pragma unroll
    for (int k = 0; k < 4; ++k)
        av[k] = __builtin_nontemporal_load((const v4f*)adj + o0 + k);
    #pragma unroll
    for (int k = 0; k < 4; ++k)
        sv[k] = sjr[jc + k];

    #pragma unroll
    for (int k = 0; k < 4; ++k) {
        v4f r;
        r.x = P_ASEM * fsigmoid(s + sv[k].x) + (1.0f - P_ASEM) * av[k].x;
        r.y = P_ASEM * fsigmoid(s + sv[k].y) + (1.0f - P_ASEM) * av[k].y;
        r.z = P_ASEM * fsigmoid(s + sv[k].z) + (1.0f - P_ASEM) * av[k].z;
        r.w = P_ASEM * fsigmoid(s + sv[k].w) + (1.0f - P_ASEM) * av[k].w;
        __builtin_nontemporal_store(r, (v4f*)out + o0 + k);
    }
}

extern "C" void kernel_launch(void* const* d_in, const int* in_sizes, int n_in,
                              void* d_out, int out_size, void* d_ws, size_t ws_size,
                              hipStream_t stream) {
    const float* x   = (const float*)d_in[0];  // [8,2048,512]
    const float* adj = (const float*)d_in[1];  // [8,2048,2048]
    const float* W   = (const float*)d_in[2];  // [1,1024]
    const float* b   = (const float*)d_in[3];  // [1]
    float* out = (float*)d_out;

    float* si = (float*)d_ws;            // B*N = 16384 floats
    float* sj = si + (PB * PN);          // B*N = 16384 floats

    // Kernel 1: B*N/4 = 4096 blocks (4 waves = 4 rows each)
    row_dots_kernel<<<(PB * PN) / 4, 256, 0, stream>>>(x, W, si, sj);

    // Kernel 2: B*N*N/16 threads (16 floats each), 8192 blocks of 256
    const size_t nthreads = (size_t)PB * PN * PN / 16;
    blend_kernel<<<(int)(nthreads / 256), 256, 0, stream>>>(adj, si, sj, b, out);
}

// Round 5
// 242.917 us; speedup vs baseline: 1.5834x; 1.5834x over previous
//
#include <hip/hip_runtime.h>
#include <hip/hip_bf16.h>

// Problem constants (from reference setup_inputs): B=8, N=2048, D=512
#define PB 8
#define PN 2048
#define PD 512
#define P_ASEM 0.6f

// Native clang vector type — required by __builtin_nontemporal_* (HIP's
// float4 is a class and is rejected).
typedef float v4f __attribute__((ext_vector_type(4)));

// ---------------------------------------------------------------------------
// Kernel 1: per-row dots. si[r] = x[r,:].Wi, sj[r] = x[r,:].Wj for r in [0,B*N)
// One wave per row; 2x v4f per lane; 64-lane butterfly reduction.
// ---------------------------------------------------------------------------
__global__ __launch_bounds__(256) void row_dots_kernel(
    const float* __restrict__ x,   // [B*N, D]
    const float* __restrict__ W,   // [2*D]
    float* __restrict__ si,        // [B*N]
    float* __restrict__ sj)        // [B*N]
{
    const int wave = threadIdx.x >> 6;            // 0..3
    const int lane = threadIdx.x & 63;
    const int row  = blockIdx.x * 4 + wave;       // grid = B*N/4

    const v4f* xr = (const v4f*)(x + (size_t)row * PD);
    const v4f* Wi = (const v4f*)(W);
    const v4f* Wj = (const v4f*)(W + PD);

    // D = 512 floats = 128 v4f; 64 lanes -> 2 v4f per lane (wave-strided)
    v4f a0  = __builtin_nontemporal_load(xr + lane);
    v4f a1  = __builtin_nontemporal_load(xr + lane + 64);
    v4f wi0 = Wi[lane];
    v4f wi1 = Wi[lane + 64];
    v4f wj0 = Wj[lane];
    v4f wj1 = Wj[lane + 64];

    float acc_i = a0.x*wi0.x + a0.y*wi0.y + a0.z*wi0.z + a0.w*wi0.w
                + a1.x*wi1.x + a1.y*wi1.y + a1.z*wi1.z + a1.w*wi1.w;
    float acc_j = a0.x*wj0.x + a0.y*wj0.y + a0.z*wj0.z + a0.w*wj0.w
                + a1.x*wj1.x + a1.y*wj1.y + a1.z*wj1.z + a1.w*wj1.w;

    #pragma unroll
    for (int off = 32; off > 0; off >>= 1) {
        acc_i += __shfl_down(acc_i, off, 64);
        acc_j += __shfl_down(acc_j, off, 64);
    }
    if (lane == 0) {
        si[row] = acc_i;
        sj[row] = acc_j;
    }
}

// ---------------------------------------------------------------------------
// Kernel 2: out[b,i,j] = 0.6*sigmoid(si[b,i]+sj[b,j]+b0) + 0.4*adj[b,i,j]
// 4x v4f per thread, WAVE-STRIDED (idx = base + k*256 + tid): every
// instruction is 256 lanes x 16B contiguous = fully coalesced. Round-4
// post-mortem: thread-contiguous layout (lane stride 64B) caused partial-line
// RMW (WRITE_SIZE 134->350MB, BW 2.1 TB/s). Never do that.
// ---------------------------------------------------------------------------
__device__ __forceinline__ float fsigmoid(float t) {
    return __frcp_rn(1.0f + __expf(-t));
}

__global__ __launch_bounds__(256) void blend_kernel(
    const float* __restrict__ adj,  // [B*N*N]
    const float* __restrict__ si,   // [B*N]
    const float* __restrict__ sj,   // [B*N]
    const float* __restrict__ bptr, // [1]
    float* __restrict__ out)        // [B*N*N]
{
    // block covers 4*256 = 1024 consecutive v4f (16 KB); thread k-th element
    // at base + k*256 (coalesced per instruction).
    const size_t base = (size_t)blockIdx.x * 1024 + threadIdx.x;
    const float bias = bptr[0];

    size_t idx[4];
    v4f av[4];
    #pragma unroll
    for (int k = 0; k < 4; ++k) {
        idx[k] = base + (size_t)k * 256;
        av[k] = __builtin_nontemporal_load((const v4f*)adj + idx[k]);
    }

    #pragma unroll
    for (int k = 0; k < 4; ++k) {
        const int row  = (int)(idx[k] >> 9);    // / (N/4=512)
        const int jc   = (int)(idx[k] & 511);
        const int bidx = row >> 11;             // / N
        const float s  = si[row] + bias;
        const v4f sv   = ((const v4f*)(sj + (size_t)bidx * PN))[jc];

        v4f r;
        r.x = P_ASEM * fsigmoid(s + sv.x) + (1.0f - P_ASEM) * av[k].x;
        r.y = P_ASEM * fsigmoid(s + sv.y) + (1.0f - P_ASEM) * av[k].y;
        r.z = P_ASEM * fsigmoid(s + sv.z) + (1.0f - P_ASEM) * av[k].z;
        r.w = P_ASEM * fsigmoid(s + sv.w) + (1.0f - P_ASEM) * av[k].w;
        __builtin_nontemporal_store(r, (v4f*)out + idx[k]);
    }
}

extern "C" void kernel_launch(void* const* d_in, const int* in_sizes, int n_in,
                              void* d_out, int out_size, void* d_ws, size_t ws_size,
                              hipStream_t stream) {
    const float* x   = (const float*)d_in[0];  // [8,2048,512]
    const float* adj = (const float*)d_in[1];  // [8,2048,2048]
    const float* W   = (const float*)d_in[2];  // [1,1024]
    const float* b   = (const float*)d_in[3];  // [1]
    float* out = (float*)d_out;

    float* si = (float*)d_ws;            // B*N = 16384 floats
    float* sj = si + (PB * PN);          // B*N = 16384 floats

    // Kernel 1: B*N/4 = 4096 blocks (4 waves = 4 rows each)
    row_dots_kernel<<<(PB * PN) / 4, 256, 0, stream>>>(x, W, si, sj);

    // Kernel 2: B*N*N/4 v4f / 1024 per block = 8192 blocks of 256
    const size_t nblocks = (size_t)PB * PN * PN / 4 / 1024;
    blend_kernel<<<(int)nblocks, 256, 0, stream>>>(adj, si, sj, b, out);
}